// Round 6
// baseline (247.767 us; speedup 1.0000x reference)
//
#include <hip/hip_runtime.h>
#include <math.h>

#define N_NODES 100000
#define N_EDGES 800000
#define DIM_IN 128
#define DIM_OUT 256
#define NPB 128   // nodes per block in the fused kernel (2 MFMA sub-tiles of 64)

typedef __bf16 bf16x8 __attribute__((ext_vector_type(8)));
typedef float  f32x4  __attribute__((ext_vector_type(4)));

// ---------------- prep: convert W to bf16 + zero counts --------------------
__global__ __launch_bounds__(256) void k_prep(const float* __restrict__ W,
                                              unsigned short* __restrict__ Wb,
                                              int* __restrict__ counts) {
    int i = blockIdx.x * 256 + threadIdx.x;
    if (i < DIM_IN * DIM_OUT) Wb[i] = __builtin_bit_cast(unsigned short, (__bf16)W[i]);
    int j = i - DIM_IN * DIM_OUT;
    if (j >= 0 && j < N_NODES) counts[j] = 0;
}

// ---------------- CSR build ------------------------------------------------
__global__ __launch_bounds__(256) void k_count(const int* __restrict__ dst,
                                               int* __restrict__ counts) {
    int e = blockIdx.x * 256 + threadIdx.x;   // grid exact: 800000/256
    atomicAdd(&counts[dst[e]], 1);
}

// 1024-thread block scan using wave shuffles.
__global__ __launch_bounds__(1024) void k_scan1(const int* __restrict__ counts,
                                                int* __restrict__ incl,
                                                int* __restrict__ bsum) {
    __shared__ int ws[16];
    int tid = threadIdx.x, lane = tid & 63, wid = tid >> 6;
    int i = blockIdx.x * 1024 + tid;
    int v = (i < N_NODES) ? counts[i] : 0;
#pragma unroll
    for (int d = 1; d < 64; d <<= 1) {
        int t = __shfl_up(v, d, 64);
        if (lane >= d) v += t;
    }
    if (lane == 63) ws[wid] = v;
    __syncthreads();
    if (wid == 0) {
        int s = (lane < 16) ? ws[lane] : 0;
#pragma unroll
        for (int d = 1; d < 16; d <<= 1) {
            int t = __shfl_up(s, d, 64);
            if (lane >= d) s += t;
        }
        if (lane < 16) ws[lane] = s;
    }
    __syncthreads();
    if (wid > 0) v += ws[wid - 1];
    if (i < N_NODES) incl[i] = v;
    if (tid == 1023) bsum[blockIdx.x] = v;
}

__global__ __launch_bounds__(128) void k_scan2(const int* __restrict__ bsum,
                                               int* __restrict__ boff) {
    __shared__ int s[128];
    int tid = threadIdx.x;
    int v = (tid < 98) ? bsum[tid] : 0;
    s[tid] = v;
    __syncthreads();
    for (int off = 1; off < 128; off <<= 1) {
        int t = (tid >= off) ? s[tid - off] : 0;
        __syncthreads();
        s[tid] += t;
        __syncthreads();
    }
    if (tid < 98) boff[tid] = s[tid];
}

__global__ __launch_bounds__(1024) void k_scan3(const int* __restrict__ counts,
                                                int* __restrict__ incl,
                                                const int* __restrict__ boff,
                                                int* __restrict__ cursor) {
    int i = blockIdx.x * 1024 + threadIdx.x;
    if (i < N_NODES) {
        int base = (blockIdx.x > 0) ? boff[blockIdx.x - 1] : 0;
        int v = incl[i] + base;
        incl[i] = v;                 // global inclusive scan
        cursor[i] = v - counts[i];   // row start (exclusive)
    }
}

__global__ __launch_bounds__(256) void k_fill(const int* __restrict__ src,
                                              const int* __restrict__ dst,
                                              int* __restrict__ cursor,
                                              int* __restrict__ csr) {
    int e = blockIdx.x * 256 + threadIdx.x;
    int pos = atomicAdd(&cursor[dst[e]], 1);
    csr[pos] = src[e];
}

// ---------------- GELU (tanh form, branch-free) ----------------------------
__device__ __forceinline__ float gelu_f(float h) {
    float u = h * h;
    float inner = h * (0.7978845608f + 0.0356774081f * u);
    float a = __builtin_amdgcn_exp2f(-2.8853900818f * __builtin_fabsf(inner));
    float t = (1.f - a) * __builtin_amdgcn_rcpf(1.f + a);
    t = __builtin_copysignf(t, inner);
    return 0.5f * h * (1.f + t);
}

// ---------------- Fused aggregate + MFMA GEMM + bias + GELU ----------------
// Block = 256 thr = 4 waves, owns NPB=128 nodes.
// Phase 1: wave w aggregates nodes [w*32, w*32+32): lane holds float2 of the
//   128-dim x row; result scaled by deg_inv, packed bf16, written to the
//   XOR-swizzled LDS m-tile (byte ^= (row&7)<<4 on both sides).
// Phase 2: wave w computes out cols [w*64, w*64+64) for all 128 nodes.
//   A = W fragments preloaded in registers BEFORE phase 1 (overlaps gather);
//   B = m fragments from LDS per-ks (small live range).
//   mfma(W,m): D[row=out, col=node] -> lane's f32x4 = 4 consecutive out
//   channels of one node -> coalescible float4 stores (no nontemporal: let
//   L2 merge 64B halves into full lines).
__global__ __launch_bounds__(256) void k_fused(
    const float* __restrict__ x,
    const int* __restrict__ csr,
    const int* __restrict__ incl,
    const int* __restrict__ counts,
    const float* __restrict__ deg_inv,
    const unsigned short* __restrict__ Wb,
    const float* __restrict__ bias,
    float* __restrict__ out)
{
    __shared__ unsigned char smem[NPB * DIM_IN * 2];   // 32 KB bf16 m-tile (swizzled)

    const int wave = threadIdx.x >> 6;
    const int lane = threadIdx.x & 63;
    const int lr = lane & 15;
    const int kg = lane >> 4;
    const int o0 = wave * 64;
    const int n_base = blockIdx.x * NPB;

    // --- preload W fragments + bias (independent of LDS; overlaps phase 1) --
    bf16x8 wfr[4][4];
#pragma unroll
    for (int mt = 0; mt < 4; ++mt)
#pragma unroll
        for (int ks = 0; ks < 4; ++ks)
            wfr[mt][ks] = *reinterpret_cast<const bf16x8*>(
                Wb + (size_t)(o0 + mt * 16 + lr) * DIM_IN + ks * 32 + kg * 8);
    f32x4 bias4[4];
#pragma unroll
    for (int mt = 0; mt < 4; ++mt)
        bias4[mt] = *reinterpret_cast<const f32x4*>(bias + o0 + mt * 16 + kg * 4);

    // --- phase 1: aggregate 32 nodes per wave into swizzled LDS ------------
    for (int i = 0; i < 32; ++i) {
        const int nl = wave * 32 + i;        // local row 0..127
        const int node = n_base + nl;
        float r0 = 0.f, r1 = 0.f;
        if (node < N_NODES) {
            int end = __builtin_amdgcn_readfirstlane(incl[node]);
            int beg = end - __builtin_amdgcn_readfirstlane(counts[node]);
            float a0 = 0.f, a1 = 0.f, b0 = 0.f, b1 = 0.f;
            int e = beg;
            for (; e + 3 < end; e += 4) {
                int s0 = csr[e], s1 = csr[e + 1], s2 = csr[e + 2], s3 = csr[e + 3];
                float2 v0 = *reinterpret_cast<const float2*>(x + (size_t)s0 * DIM_IN + lane * 2);
                float2 v1 = *reinterpret_cast<const float2*>(x + (size_t)s1 * DIM_IN + lane * 2);
                float2 v2 = *reinterpret_cast<const float2*>(x + (size_t)s2 * DIM_IN + lane * 2);
                float2 v3 = *reinterpret_cast<const float2*>(x + (size_t)s3 * DIM_IN + lane * 2);
                a0 += v0.x; a1 += v0.y;
                b0 += v1.x; b1 += v1.y;
                a0 += v2.x; a1 += v2.y;
                b0 += v3.x; b1 += v3.y;
            }
            for (; e < end; ++e) {
                int s0 = csr[e];
                float2 v0 = *reinterpret_cast<const float2*>(x + (size_t)s0 * DIM_IN + lane * 2);
                a0 += v0.x; a1 += v0.y;
            }
            float d = deg_inv[node];
            r0 = (a0 + b0) * d;
            r1 = (a1 + b1) * d;
        }
        unsigned short q0 = __builtin_bit_cast(unsigned short, (__bf16)r0);
        unsigned short q1 = __builtin_bit_cast(unsigned short, (__bf16)r1);
        unsigned packed = (unsigned)q0 | ((unsigned)q1 << 16);
        unsigned boff = (unsigned)(nl * 256) + (((unsigned)lane * 4u) ^ (((unsigned)nl & 7u) << 4));
        *reinterpret_cast<unsigned*>(smem + boff) = packed;
    }
    __syncthreads();

    // --- phase 2: MFMA GEMM from LDS ---------------------------------------
#pragma unroll
    for (int st = 0; st < NPB / 64; ++st) {
        const int n0 = n_base + st * 64;
        if (n0 >= N_NODES) break;

        f32x4 acc[4][4] = {};
#pragma unroll
        for (int ks = 0; ks < 4; ++ks) {
            bf16x8 mfr[4];
#pragma unroll
            for (int nt = 0; nt < 4; ++nt) {
                const int r = st * 64 + nt * 16 + lr;            // r&7 == lr&7
                const unsigned roff = (unsigned)(r * 256) +
                    ((unsigned)(ks * 64 + kg * 16) ^ (((unsigned)r & 7u) << 4));
                mfr[nt] = *reinterpret_cast<const bf16x8*>(smem + roff);
            }
#pragma unroll
            for (int mt = 0; mt < 4; ++mt)
#pragma unroll
                for (int nt = 0; nt < 4; ++nt)
                    acc[mt][nt] = __builtin_amdgcn_mfma_f32_16x16x32_bf16(
                        wfr[mt][ks], mfr[nt], acc[mt][nt], 0, 0, 0);
        }

        // Epilogue: D col = lane&15 = node, row = kg*4 + reg = out-within-16.
#pragma unroll
        for (int nt = 0; nt < 4; ++nt) {
            int node = n0 + nt * 16 + lr;
            if (node < N_NODES) {
                float* orow = out + (size_t)node * DIM_OUT + o0 + kg * 4;
#pragma unroll
                for (int mt = 0; mt < 4; ++mt) {
                    f32x4 h = acc[mt][nt] + bias4[mt];
                    f32x4 g;
                    g[0] = gelu_f(h[0]);
                    g[1] = gelu_f(h[1]);
                    g[2] = gelu_f(h[2]);
                    g[3] = gelu_f(h[3]);
                    *reinterpret_cast<f32x4*>(orow + mt * 16) = g;
                }
            }
        }
    }
}

extern "C" void kernel_launch(void* const* d_in, const int* in_sizes, int n_in,
                              void* d_out, int out_size, void* d_ws, size_t ws_size,
                              hipStream_t stream) {
    const float* x       = (const float*)d_in[0];
    const int*   ei      = (const int*)d_in[1];
    const float* deg_inv = (const float*)d_in[2];
    const float* W       = (const float*)d_in[3];
    const float* bias    = (const float*)d_in[4];
    float*       out     = (float*)d_out;

    const int* src = ei;
    const int* dst = ei + N_EDGES;

    // ws layout: counts | incl | cursor | bsum | boff | csr | Wb
    int* counts = (int*)d_ws;
    int* incl   = counts + N_NODES;
    int* cursor = incl + N_NODES;
    int* bsum   = cursor + N_NODES;
    int* boff   = bsum + 128;
    int* csr    = boff + 128;
    unsigned short* Wb = (unsigned short*)(csr + N_EDGES);

    k_prep <<<(DIM_IN * DIM_OUT + N_NODES + 255) / 256, 256, 0, stream>>>(W, Wb, counts);
    k_count<<<N_EDGES / 256, 256, 0, stream>>>(dst, counts);
    k_scan1<<<(N_NODES + 1023) / 1024, 1024, 0, stream>>>(counts, incl, bsum);
    k_scan2<<<1, 128, 0, stream>>>(bsum, boff);
    k_scan3<<<(N_NODES + 1023) / 1024, 1024, 0, stream>>>(counts, incl, boff, cursor);
    k_fill <<<N_EDGES / 256, 256, 0, stream>>>(src, dst, cursor, csr);
    k_fused<<<(N_NODES + NPB - 1) / NPB, 256, 0, stream>>>(x, csr, incl, counts,
                                                           deg_inv, Wb, bias, out);
}

// Round 7
// 217.070 us; speedup vs baseline: 1.1414x; 1.1414x over previous
//
#include <hip/hip_runtime.h>
#include <math.h>

#define N_NODES 100000
#define N_EDGES 800000
#define DIM_IN 128
#define DIM_OUT 256
#define NPB 32    // nodes per block in the MFMA GEMM: 100000 = 3125 * 32 exactly

typedef __bf16 bf16x8 __attribute__((ext_vector_type(8)));
typedef float  f32x4  __attribute__((ext_vector_type(4)));

// ---------------- prep: convert W to bf16 + zero counts --------------------
__global__ __launch_bounds__(256) void k_prep(const float* __restrict__ W,
                                              unsigned short* __restrict__ Wb,
                                              int* __restrict__ counts) {
    int i = blockIdx.x * 256 + threadIdx.x;
    if (i < DIM_IN * DIM_OUT) Wb[i] = __builtin_bit_cast(unsigned short, (__bf16)W[i]);
    int j = i - DIM_IN * DIM_OUT;
    if (j >= 0 && j < N_NODES) counts[j] = 0;
}

// ---------------- CSR build ------------------------------------------------
__global__ __launch_bounds__(256) void k_count(const int* __restrict__ dst,
                                               int* __restrict__ counts) {
    int e = blockIdx.x * 256 + threadIdx.x;   // grid exact: 800000/256
    atomicAdd(&counts[dst[e]], 1);
}

// 1024-thread block scan using wave shuffles.
__global__ __launch_bounds__(1024) void k_scan1(const int* __restrict__ counts,
                                                int* __restrict__ incl,
                                                int* __restrict__ bsum) {
    __shared__ int ws[16];
    int tid = threadIdx.x, lane = tid & 63, wid = tid >> 6;
    int i = blockIdx.x * 1024 + tid;
    int v = (i < N_NODES) ? counts[i] : 0;
#pragma unroll
    for (int d = 1; d < 64; d <<= 1) {
        int t = __shfl_up(v, d, 64);
        if (lane >= d) v += t;
    }
    if (lane == 63) ws[wid] = v;
    __syncthreads();
    if (wid == 0) {
        int s = (lane < 16) ? ws[lane] : 0;
#pragma unroll
        for (int d = 1; d < 16; d <<= 1) {
            int t = __shfl_up(s, d, 64);
            if (lane >= d) s += t;
        }
        if (lane < 16) ws[lane] = s;
    }
    __syncthreads();
    if (wid > 0) v += ws[wid - 1];
    if (i < N_NODES) incl[i] = v;
    if (tid == 1023) bsum[blockIdx.x] = v;
}

__global__ __launch_bounds__(128) void k_scan2(const int* __restrict__ bsum,
                                               int* __restrict__ boff) {
    __shared__ int s[128];
    int tid = threadIdx.x;
    int v = (tid < 98) ? bsum[tid] : 0;
    s[tid] = v;
    __syncthreads();
    for (int off = 1; off < 128; off <<= 1) {
        int t = (tid >= off) ? s[tid - off] : 0;
        __syncthreads();
        s[tid] += t;
        __syncthreads();
    }
    if (tid < 98) boff[tid] = s[tid];
}

__global__ __launch_bounds__(1024) void k_scan3(const int* __restrict__ counts,
                                                int* __restrict__ incl,
                                                const int* __restrict__ boff,
                                                int* __restrict__ cursor) {
    int i = blockIdx.x * 1024 + threadIdx.x;
    if (i < N_NODES) {
        int base = (blockIdx.x > 0) ? boff[blockIdx.x - 1] : 0;
        int v = incl[i] + base;
        incl[i] = v;                 // global inclusive scan
        cursor[i] = v - counts[i];   // row start (exclusive)
    }
}

__global__ __launch_bounds__(256) void k_fill(const int* __restrict__ src,
                                              const int* __restrict__ dst,
                                              int* __restrict__ cursor,
                                              int* __restrict__ csr) {
    int e = blockIdx.x * 256 + threadIdx.x;
    int pos = atomicAdd(&cursor[dst[e]], 1);
    csr[pos] = src[e];
}

// ---------------- Aggregate: mb[n] = bf16(deg_inv[n] * sum x[src]) ---------
// One wave per node (100k waves of TLP); lane holds float2 of the row;
// unroll x4 with two accumulator chains for load ILP.
__global__ __launch_bounds__(256) void k_agg(const float* __restrict__ x,
                                             const int* __restrict__ csr,
                                             const int* __restrict__ incl,
                                             const int* __restrict__ counts,
                                             const float* __restrict__ deg_inv,
                                             unsigned short* __restrict__ mb) {
    int wave = threadIdx.x >> 6;
    int lane = threadIdx.x & 63;
    int node = blockIdx.x * 4 + wave;        // grid exact: 25000*4
    int end = __builtin_amdgcn_readfirstlane(incl[node]);
    int beg = end - __builtin_amdgcn_readfirstlane(counts[node]);
    float a0 = 0.f, a1 = 0.f, b0 = 0.f, b1 = 0.f;
    int e = beg;
    for (; e + 3 < end; e += 4) {
        int s0 = csr[e], s1 = csr[e + 1], s2 = csr[e + 2], s3 = csr[e + 3];
        float2 v0 = *reinterpret_cast<const float2*>(x + (size_t)s0 * DIM_IN + lane * 2);
        float2 v1 = *reinterpret_cast<const float2*>(x + (size_t)s1 * DIM_IN + lane * 2);
        float2 v2 = *reinterpret_cast<const float2*>(x + (size_t)s2 * DIM_IN + lane * 2);
        float2 v3 = *reinterpret_cast<const float2*>(x + (size_t)s3 * DIM_IN + lane * 2);
        a0 += v0.x; a1 += v0.y;
        b0 += v1.x; b1 += v1.y;
        a0 += v2.x; a1 += v2.y;
        b0 += v3.x; b1 += v3.y;
    }
    for (; e < end; ++e) {
        int s0 = csr[e];
        float2 v0 = *reinterpret_cast<const float2*>(x + (size_t)s0 * DIM_IN + lane * 2);
        a0 += v0.x; a1 += v0.y;
    }
    float d = deg_inv[node];
    float r0 = (a0 + b0) * d;
    float r1 = (a1 + b1) * d;
    unsigned short q0 = __builtin_bit_cast(unsigned short, (__bf16)r0);
    unsigned short q1 = __builtin_bit_cast(unsigned short, (__bf16)r1);
    reinterpret_cast<unsigned*>(mb + (size_t)node * DIM_IN)[lane] =
        (unsigned)q0 | ((unsigned)q1 << 16);
}

// ---------------- GELU (tanh form, branch-free) ----------------------------
__device__ __forceinline__ float gelu_f(float h) {
    float u = h * h;
    float inner = h * (0.7978845608f + 0.0356774081f * u);
    float a = __builtin_amdgcn_exp2f(-2.8853900818f * __builtin_fabsf(inner));
    float t = (1.f - a) * __builtin_amdgcn_rcpf(1.f + a);
    t = __builtin_copysignf(t, inner);
    return 0.5f * h * (1.f + t);
}

// ---------------- MFMA GEMM + bias + GELU (swapped operands) ---------------
// 512 thr = 8 waves; block owns 32 nodes (exact: 3125 blocks), wave w owns
// out cols [w*32, w*32+32). mfma(A=W_frag, B=m_frag):
//   A row = lr -> out = o0+mt*16+lr, k = ks*32+kg*8
//   B col = lr -> node = nb+nt*16+lr, k = ks*32+kg*8
//   D: col = lane&15 = node, row = kg*4+r = out-within-16
// Lane's f32x4 = 4 consecutive out channels of one node -> plain float4
// stores (NT store proved to inflate WRITE_SIZE 1.4x in round 5).
__global__ __launch_bounds__(512) void k_gemm(
    const unsigned short* __restrict__ mb,
    const unsigned short* __restrict__ Wb,
    const float* __restrict__ bias,
    float* __restrict__ out)
{
    const int wave = threadIdx.x >> 6;
    const int lane = threadIdx.x & 63;
    const int lr = lane & 15;
    const int kg = lane >> 4;
    const int o0 = wave * 32;
    const int nb = blockIdx.x * NPB;

    bf16x8 wfr[2][4];
#pragma unroll
    for (int mt = 0; mt < 2; ++mt)
#pragma unroll
        for (int ks = 0; ks < 4; ++ks)
            wfr[mt][ks] = *reinterpret_cast<const bf16x8*>(
                Wb + (size_t)(o0 + mt * 16 + lr) * DIM_IN + ks * 32 + kg * 8);

    f32x4 bias4[2];
#pragma unroll
    for (int mt = 0; mt < 2; ++mt)
        bias4[mt] = *reinterpret_cast<const f32x4*>(bias + o0 + mt * 16 + kg * 4);

    bf16x8 mfr[2][4];
#pragma unroll
    for (int nt = 0; nt < 2; ++nt) {
        const unsigned short* brow = mb + (size_t)(nb + nt * 16 + lr) * DIM_IN;
#pragma unroll
        for (int ks = 0; ks < 4; ++ks)
            mfr[nt][ks] = *reinterpret_cast<const bf16x8*>(brow + ks * 32 + kg * 8);
    }

    f32x4 acc[2][2] = {};
#pragma unroll
    for (int ks = 0; ks < 4; ++ks)
#pragma unroll
        for (int mt = 0; mt < 2; ++mt)
#pragma unroll
            for (int nt = 0; nt < 2; ++nt)
                acc[mt][nt] = __builtin_amdgcn_mfma_f32_16x16x32_bf16(
                    wfr[mt][ks], mfr[nt][ks], acc[mt][nt], 0, 0, 0);

#pragma unroll
    for (int nt = 0; nt < 2; ++nt) {
        const int node = nb + nt * 16 + lr;
        float* orow = out + (size_t)node * DIM_OUT + o0 + kg * 4;
#pragma unroll
        for (int mt = 0; mt < 2; ++mt) {
            f32x4 h = acc[mt][nt] + bias4[mt];
            f32x4 g;
            g[0] = gelu_f(h[0]);
            g[1] = gelu_f(h[1]);
            g[2] = gelu_f(h[2]);
            g[3] = gelu_f(h[3]);
            *reinterpret_cast<f32x4*>(orow + mt * 16) = g;
        }
    }
}

extern "C" void kernel_launch(void* const* d_in, const int* in_sizes, int n_in,
                              void* d_out, int out_size, void* d_ws, size_t ws_size,
                              hipStream_t stream) {
    const float* x       = (const float*)d_in[0];
    const int*   ei      = (const int*)d_in[1];
    const float* deg_inv = (const float*)d_in[2];
    const float* W       = (const float*)d_in[3];
    const float* bias    = (const float*)d_in[4];
    float*       out     = (float*)d_out;

    const int* src = ei;
    const int* dst = ei + N_EDGES;

    // ws layout: mb | counts | incl | cursor | bsum | boff | csr | Wb
    unsigned short* mb = (unsigned short*)d_ws;
    size_t mb_bytes = (size_t)N_NODES * DIM_IN * sizeof(unsigned short);   // 25.6 MB
    int* counts = (int*)((char*)d_ws + mb_bytes);
    int* incl   = counts + N_NODES;
    int* cursor = incl + N_NODES;
    int* bsum   = cursor + N_NODES;
    int* boff   = bsum + 128;
    int* csr    = boff + 128;
    unsigned short* Wb = (unsigned short*)(csr + N_EDGES);

    k_prep <<<(DIM_IN * DIM_OUT + N_NODES + 255) / 256, 256, 0, stream>>>(W, Wb, counts);
    k_count<<<N_EDGES / 256, 256, 0, stream>>>(dst, counts);
    k_scan1<<<(N_NODES + 1023) / 1024, 1024, 0, stream>>>(counts, incl, bsum);
    k_scan2<<<1, 128, 0, stream>>>(bsum, boff);
    k_scan3<<<(N_NODES + 1023) / 1024, 1024, 0, stream>>>(counts, incl, boff, cursor);
    k_fill <<<N_EDGES / 256, 256, 0, stream>>>(src, dst, cursor, csr);
    k_agg  <<<N_NODES / 4, 256, 0, stream>>>(x, csr, incl, counts, deg_inv, mb);
    k_gemm <<<N_NODES / NPB, 512, 0, stream>>>(mb, Wb, bias, out);
}

// Round 8
// 192.426 us; speedup vs baseline: 1.2876x; 1.1281x over previous
//
#include <hip/hip_runtime.h>
#include <math.h>

#define N_NODES 100000
#define N_EDGES 800000
#define DIM_IN 128
#define DIM_OUT 256
#define NPB 128   // nodes per GEMM block: 4 sub-tiles of 32

typedef __bf16 bf16x8 __attribute__((ext_vector_type(8)));
typedef float  f32x4  __attribute__((ext_vector_type(4)));

// ---------------- prep: cvtX (f32->bf16) + cvtW + zero counts --------------
// grid exact: 12500*256 threads = 3.2M float4 elements of x.
__global__ __launch_bounds__(256) void k_prep(const float* __restrict__ x,
                                              const float* __restrict__ W,
                                              unsigned short* __restrict__ xb,
                                              unsigned short* __restrict__ Wb,
                                              int* __restrict__ counts) {
    int i = blockIdx.x * 256 + threadIdx.x;
    const float4 v = reinterpret_cast<const float4*>(x)[i];
    unsigned short s0 = __builtin_bit_cast(unsigned short, (__bf16)v.x);
    unsigned short s1 = __builtin_bit_cast(unsigned short, (__bf16)v.y);
    unsigned short s2 = __builtin_bit_cast(unsigned short, (__bf16)v.z);
    unsigned short s3 = __builtin_bit_cast(unsigned short, (__bf16)v.w);
    uint2 o;
    o.x = (unsigned)s0 | ((unsigned)s1 << 16);
    o.y = (unsigned)s2 | ((unsigned)s3 << 16);
    reinterpret_cast<uint2*>(xb)[i] = o;
    if (i < DIM_IN * DIM_OUT) Wb[i] = __builtin_bit_cast(unsigned short, (__bf16)W[i]);
    if (i < N_NODES) counts[i] = 0;
}

// ---------------- CSR build ------------------------------------------------
__global__ __launch_bounds__(256) void k_count(const int* __restrict__ dst,
                                               int* __restrict__ counts) {
    int e = blockIdx.x * 256 + threadIdx.x;   // grid exact: 800000/256
    atomicAdd(&counts[dst[e]], 1);
}

// 1024-thread block scan using wave shuffles.
__global__ __launch_bounds__(1024) void k_scan1(const int* __restrict__ counts,
                                                int* __restrict__ incl,
                                                int* __restrict__ bsum) {
    __shared__ int ws[16];
    int tid = threadIdx.x, lane = tid & 63, wid = tid >> 6;
    int i = blockIdx.x * 1024 + tid;
    int v = (i < N_NODES) ? counts[i] : 0;
#pragma unroll
    for (int d = 1; d < 64; d <<= 1) {
        int t = __shfl_up(v, d, 64);
        if (lane >= d) v += t;
    }
    if (lane == 63) ws[wid] = v;
    __syncthreads();
    if (wid == 0) {
        int s = (lane < 16) ? ws[lane] : 0;
#pragma unroll
        for (int d = 1; d < 16; d <<= 1) {
            int t = __shfl_up(s, d, 64);
            if (lane >= d) s += t;
        }
        if (lane < 16) ws[lane] = s;
    }
    __syncthreads();
    if (wid > 0) v += ws[wid - 1];
    if (i < N_NODES) incl[i] = v;
    if (tid == 1023) bsum[blockIdx.x] = v;
}

__global__ __launch_bounds__(128) void k_scan2(const int* __restrict__ bsum,
                                               int* __restrict__ boff) {
    __shared__ int s[128];
    int tid = threadIdx.x;
    int v = (tid < 98) ? bsum[tid] : 0;
    s[tid] = v;
    __syncthreads();
    for (int off = 1; off < 128; off <<= 1) {
        int t = (tid >= off) ? s[tid - off] : 0;
        __syncthreads();
        s[tid] += t;
        __syncthreads();
    }
    if (tid < 98) boff[tid] = s[tid];
}

__global__ __launch_bounds__(1024) void k_scan3(const int* __restrict__ counts,
                                                int* __restrict__ incl,
                                                const int* __restrict__ boff,
                                                int* __restrict__ cursor) {
    int i = blockIdx.x * 1024 + threadIdx.x;
    if (i < N_NODES) {
        int base = (blockIdx.x > 0) ? boff[blockIdx.x - 1] : 0;
        int v = incl[i] + base;
        incl[i] = v;                 // global inclusive scan
        cursor[i] = v - counts[i];   // row start (exclusive)
    }
}

__global__ __launch_bounds__(256) void k_fill(const int* __restrict__ src,
                                              const int* __restrict__ dst,
                                              int* __restrict__ cursor,
                                              int* __restrict__ csr) {
    int e = blockIdx.x * 256 + threadIdx.x;
    int pos = atomicAdd(&cursor[dst[e]], 1);
    csr[pos] = src[e];
}

// ---------------- Aggregate: mb[n] = bf16(deg_inv[n] * sum xb[src]) --------
// One wave per node (100k waves of TLP); lane holds one packed bf16x2 (4 B)
// of the 256 B row -> one fully-coalesced 256 B read per edge. x4 unroll.
__device__ __forceinline__ float bflo(unsigned u) {
    return __builtin_bit_cast(float, u << 16);
}
__device__ __forceinline__ float bfhi(unsigned u) {
    return __builtin_bit_cast(float, u & 0xffff0000u);
}

__global__ __launch_bounds__(256) void k_agg(const unsigned short* __restrict__ xb,
                                             const int* __restrict__ csr,
                                             const int* __restrict__ incl,
                                             const int* __restrict__ counts,
                                             const float* __restrict__ deg_inv,
                                             unsigned short* __restrict__ mb) {
    int wave = threadIdx.x >> 6;
    int lane = threadIdx.x & 63;
    int node = blockIdx.x * 4 + wave;        // grid exact: 25000*4
    int end = __builtin_amdgcn_readfirstlane(incl[node]);
    int beg = end - __builtin_amdgcn_readfirstlane(counts[node]);
    float a0 = 0.f, a1 = 0.f, b0 = 0.f, b1 = 0.f;
    int e = beg;
    for (; e + 3 < end; e += 4) {
        int s0 = csr[e], s1 = csr[e + 1], s2 = csr[e + 2], s3 = csr[e + 3];
        unsigned u0 = reinterpret_cast<const unsigned*>(xb + (size_t)s0 * DIM_IN)[lane];
        unsigned u1 = reinterpret_cast<const unsigned*>(xb + (size_t)s1 * DIM_IN)[lane];
        unsigned u2 = reinterpret_cast<const unsigned*>(xb + (size_t)s2 * DIM_IN)[lane];
        unsigned u3 = reinterpret_cast<const unsigned*>(xb + (size_t)s3 * DIM_IN)[lane];
        a0 += bflo(u0) + bflo(u1);
        a1 += bfhi(u0) + bfhi(u1);
        b0 += bflo(u2) + bflo(u3);
        b1 += bfhi(u2) + bfhi(u3);
    }
    for (; e < end; ++e) {
        int s0 = csr[e];
        unsigned u0 = reinterpret_cast<const unsigned*>(xb + (size_t)s0 * DIM_IN)[lane];
        a0 += bflo(u0);
        a1 += bfhi(u0);
    }
    float d = deg_inv[node];
    float r0 = (a0 + b0) * d;
    float r1 = (a1 + b1) * d;
    unsigned short q0 = __builtin_bit_cast(unsigned short, (__bf16)r0);
    unsigned short q1 = __builtin_bit_cast(unsigned short, (__bf16)r1);
    reinterpret_cast<unsigned*>(mb + (size_t)node * DIM_IN)[lane] =
        (unsigned)q0 | ((unsigned)q1 << 16);
}

// ---------------- GELU (tanh form, branch-free) ----------------------------
__device__ __forceinline__ float gelu_f(float h) {
    float u = h * h;
    float inner = h * (0.7978845608f + 0.0356774081f * u);
    float a = __builtin_amdgcn_exp2f(-2.8853900818f * __builtin_fabsf(inner));
    float t = (1.f - a) * __builtin_amdgcn_rcpf(1.f + a);
    t = __builtin_copysignf(t, inner);
    return 0.5f * h * (1.f + t);
}

// ---------------- MFMA GEMM + bias + GELU ----------------------------------
// 512 thr = 8 waves; block owns NPB=128 nodes in 4 sub-tiles of 32; wave w
// owns out cols [w*32, w*32+32). W fragments + bias loaded ONCE per block.
// mfma(A=W_frag, B=m_frag): D col = lane&15 = node, row = kg*4+reg = out;
// lane's f32x4 = 4 consecutive out channels of one node -> plain float4 store.
// 100000 % 32 == 0 -> no per-node clamps, only a sub-tile break.
__global__ __launch_bounds__(512) void k_gemm(
    const unsigned short* __restrict__ mb,
    const unsigned short* __restrict__ Wb,
    const float* __restrict__ bias,
    float* __restrict__ out)
{
    const int wave = threadIdx.x >> 6;
    const int lane = threadIdx.x & 63;
    const int lr = lane & 15;
    const int kg = lane >> 4;
    const int o0 = wave * 32;
    const int nb0 = blockIdx.x * NPB;

    bf16x8 wfr[2][4];
#pragma unroll
    for (int mt = 0; mt < 2; ++mt)
#pragma unroll
        for (int ks = 0; ks < 4; ++ks)
            wfr[mt][ks] = *reinterpret_cast<const bf16x8*>(
                Wb + (size_t)(o0 + mt * 16 + lr) * DIM_IN + ks * 32 + kg * 8);

    f32x4 bias4[2];
#pragma unroll
    for (int mt = 0; mt < 2; ++mt)
        bias4[mt] = *reinterpret_cast<const f32x4*>(bias + o0 + mt * 16 + kg * 4);

#pragma unroll
    for (int st = 0; st < NPB / 32; ++st) {
        const int nb = nb0 + st * 32;
        if (nb >= N_NODES) break;

        bf16x8 mfr[2][4];
#pragma unroll
        for (int nt = 0; nt < 2; ++nt) {
            const unsigned short* brow = mb + (size_t)(nb + nt * 16 + lr) * DIM_IN;
#pragma unroll
            for (int ks = 0; ks < 4; ++ks)
                mfr[nt][ks] = *reinterpret_cast<const bf16x8*>(brow + ks * 32 + kg * 8);
        }

        f32x4 acc[2][2] = {};
#pragma unroll
        for (int ks = 0; ks < 4; ++ks)
#pragma unroll
            for (int mt = 0; mt < 2; ++mt)
#pragma unroll
                for (int nt = 0; nt < 2; ++nt)
                    acc[mt][nt] = __builtin_amdgcn_mfma_f32_16x16x32_bf16(
                        wfr[mt][ks], mfr[nt][ks], acc[mt][nt], 0, 0, 0);

#pragma unroll
        for (int nt = 0; nt < 2; ++nt) {
            const int node = nb + nt * 16 + lr;
            float* orow = out + (size_t)node * DIM_OUT + o0 + kg * 4;
#pragma unroll
            for (int mt = 0; mt < 2; ++mt) {
                f32x4 h = acc[mt][nt] + bias4[mt];
                f32x4 g;
                g[0] = gelu_f(h[0]);
                g[1] = gelu_f(h[1]);
                g[2] = gelu_f(h[2]);
                g[3] = gelu_f(h[3]);
                *reinterpret_cast<f32x4*>(orow + mt * 16) = g;
            }
        }
    }
}

extern "C" void kernel_launch(void* const* d_in, const int* in_sizes, int n_in,
                              void* d_out, int out_size, void* d_ws, size_t ws_size,
                              hipStream_t stream) {
    const float* x       = (const float*)d_in[0];
    const int*   ei      = (const int*)d_in[1];
    const float* deg_inv = (const float*)d_in[2];
    const float* W       = (const float*)d_in[3];
    const float* bias    = (const float*)d_in[4];
    float*       out     = (float*)d_out;

    const int* src = ei;
    const int* dst = ei + N_EDGES;

    // ws layout (proven to fit in round 3, 55.7 MB):
    // mb | counts | incl | cursor | bsum | boff | csr | Wb | xb
    unsigned short* mb = (unsigned short*)d_ws;
    size_t mb_bytes = (size_t)N_NODES * DIM_IN * sizeof(unsigned short);   // 25.6 MB
    int* counts = (int*)((char*)d_ws + mb_bytes);
    int* incl   = counts + N_NODES;
    int* cursor = incl + N_NODES;
    int* bsum   = cursor + N_NODES;
    int* boff   = bsum + 128;
    int* csr    = boff + 128;
    unsigned short* Wb = (unsigned short*)(csr + N_EDGES);
    unsigned short* xb = Wb + DIM_IN * DIM_OUT;

    k_prep <<<(N_NODES * DIM_IN / 4) / 256, 256, 0, stream>>>(x, W, xb, Wb, counts);
    k_count<<<N_EDGES / 256, 256, 0, stream>>>(dst, counts);
    k_scan1<<<(N_NODES + 1023) / 1024, 1024, 0, stream>>>(counts, incl, bsum);
    k_scan2<<<1, 128, 0, stream>>>(bsum, boff);
    k_scan3<<<(N_NODES + 1023) / 1024, 1024, 0, stream>>>(counts, incl, boff, cursor);
    k_fill <<<N_EDGES / 256, 256, 0, stream>>>(src, dst, cursor, csr);
    k_agg  <<<N_NODES / 4, 256, 0, stream>>>(xb, csr, incl, counts, deg_inv, mb);
    k_gemm <<<(N_NODES + NPB - 1) / NPB, 512, 0, stream>>>(mb, Wb, bias, out);
}

// Round 9
// 189.885 us; speedup vs baseline: 1.3048x; 1.0134x over previous
//
#include <hip/hip_runtime.h>
#include <math.h>

#define N_NODES 100000
#define N_EDGES 800000
#define DIM_IN 128
#define DIM_OUT 256
#define NPB 64     // nodes per GEMM block: 2 sub-tiles of 32
#define SCAN_NB 98 // ceil(100000/1024)

typedef __bf16 bf16x8 __attribute__((ext_vector_type(8)));
typedef float  f32x4  __attribute__((ext_vector_type(4)));

// ---------------- prep: cvtX + cvtW + dst-count (counts pre-zeroed) --------
// grid exact: 12500*256 = 3.2M threads = x float4 elements.
__global__ __launch_bounds__(256) void k_prep(const float* __restrict__ x,
                                              const float* __restrict__ W,
                                              const int* __restrict__ dst,
                                              unsigned short* __restrict__ xb,
                                              unsigned short* __restrict__ Wb,
                                              int* __restrict__ counts) {
    int i = blockIdx.x * 256 + threadIdx.x;
    const float4 v = reinterpret_cast<const float4*>(x)[i];
    unsigned short s0 = __builtin_bit_cast(unsigned short, (__bf16)v.x);
    unsigned short s1 = __builtin_bit_cast(unsigned short, (__bf16)v.y);
    unsigned short s2 = __builtin_bit_cast(unsigned short, (__bf16)v.z);
    unsigned short s3 = __builtin_bit_cast(unsigned short, (__bf16)v.w);
    uint2 o;
    o.x = (unsigned)s0 | ((unsigned)s1 << 16);
    o.y = (unsigned)s2 | ((unsigned)s3 << 16);
    reinterpret_cast<uint2*>(xb)[i] = o;
    if (i < DIM_IN * DIM_OUT) Wb[i] = __builtin_bit_cast(unsigned short, (__bf16)W[i]);
    if (i < N_EDGES) atomicAdd(&counts[dst[i]], 1);
}

// ---------------- single-dispatch decoupled-lookback scan ------------------
// 98 blocks x 1024 thr; all co-resident on 256 CUs -> spin-wait is safe.
// state[b]: 0 = not ready; flag(bits30-31)=1 -> aggregate; =2 -> inclusive.
__global__ __launch_bounds__(1024) void k_scan(const int* __restrict__ counts,
                                               int* __restrict__ incl,
                                               int* __restrict__ cursor,
                                               unsigned* __restrict__ state) {
    __shared__ int ws[16];
    __shared__ int sExc;
    const int tid = threadIdx.x, lane = tid & 63, wid = tid >> 6;
    const int b = blockIdx.x;
    const int i = b * 1024 + tid;
    const int c = (i < N_NODES) ? counts[i] : 0;
    int v = c;
#pragma unroll
    for (int d = 1; d < 64; d <<= 1) {
        int t = __shfl_up(v, d, 64);
        if (lane >= d) v += t;
    }
    if (lane == 63) ws[wid] = v;
    __syncthreads();
    if (wid == 0) {
        int s = (lane < 16) ? ws[lane] : 0;
#pragma unroll
        for (int d = 1; d < 16; d <<= 1) {
            int t = __shfl_up(s, d, 64);
            if (lane >= d) s += t;
        }
        if (lane < 16) ws[lane] = s;
    }
    __syncthreads();
    const int total = ws[15];
    if (wid > 0) v += ws[wid - 1];
    if (tid == 0 && b > 0)
        __hip_atomic_store(&state[b], (1u << 30) | (unsigned)total,
                           __ATOMIC_RELEASE, __HIP_MEMORY_SCOPE_AGENT);
    if (wid == 0) {
        int exclusive = 0;
        if (b > 0) {
            int look = b - 1;
            for (;;) {
                int idx = look - lane;
                unsigned s;
                bool rdy;
                do {
                    s = (idx >= 0) ? __hip_atomic_load(&state[idx], __ATOMIC_ACQUIRE,
                                                       __HIP_MEMORY_SCOPE_AGENT)
                                   : (2u << 30);
                    rdy = (s >> 30) != 0u;
                } while (!__all(rdy));
                unsigned long long incmask = __ballot((s >> 30) == 2u);
                int firstInc = (incmask == 0ull) ? 64 : (__ffsll(incmask) - 1);
                int contrib = (lane <= firstInc) ? (int)(s & 0x3FFFFFFFu) : 0;
#pragma unroll
                for (int d = 32; d >= 1; d >>= 1) contrib += __shfl_down(contrib, d, 64);
                contrib = __shfl(contrib, 0, 64);
                exclusive += contrib;
                if (firstInc < 64) break;   // found an inclusive predecessor
                look -= 64;                 // window exhausted: step back
            }
        }
        if (lane == 0) {
            sExc = exclusive;
            __hip_atomic_store(&state[b], (2u << 30) | (unsigned)(exclusive + total),
                               __ATOMIC_RELEASE, __HIP_MEMORY_SCOPE_AGENT);
        }
    }
    __syncthreads();
    v += sExc;
    if (i < N_NODES) {
        incl[i] = v;          // global inclusive scan
        cursor[i] = v - c;    // row start (exclusive)
    }
}

__global__ __launch_bounds__(256) void k_fill(const int* __restrict__ src,
                                              const int* __restrict__ dst,
                                              int* __restrict__ cursor,
                                              int* __restrict__ csr) {
    int e = blockIdx.x * 256 + threadIdx.x;   // grid exact: 800000/256
    int pos = atomicAdd(&cursor[dst[e]], 1);
    csr[pos] = src[e];
}

// ---------------- Aggregate: mb[n] = bf16(deg_inv[n] * sum xb[src]) --------
__device__ __forceinline__ float bflo(unsigned u) {
    return __builtin_bit_cast(float, u << 16);
}
__device__ __forceinline__ float bfhi(unsigned u) {
    return __builtin_bit_cast(float, u & 0xffff0000u);
}

__global__ __launch_bounds__(256) void k_agg(const unsigned short* __restrict__ xb,
                                             const int* __restrict__ csr,
                                             const int* __restrict__ incl,
                                             const int* __restrict__ counts,
                                             const float* __restrict__ deg_inv,
                                             unsigned short* __restrict__ mb) {
    int wave = threadIdx.x >> 6;
    int lane = threadIdx.x & 63;
    int node = blockIdx.x * 4 + wave;        // grid exact: 25000*4
    int end = __builtin_amdgcn_readfirstlane(incl[node]);
    int beg = end - __builtin_amdgcn_readfirstlane(counts[node]);
    float a0 = 0.f, a1 = 0.f, b0 = 0.f, b1 = 0.f;
    int e = beg;
    for (; e + 3 < end; e += 4) {
        int s0 = csr[e], s1 = csr[e + 1], s2 = csr[e + 2], s3 = csr[e + 3];
        unsigned u0 = reinterpret_cast<const unsigned*>(xb + (size_t)s0 * DIM_IN)[lane];
        unsigned u1 = reinterpret_cast<const unsigned*>(xb + (size_t)s1 * DIM_IN)[lane];
        unsigned u2 = reinterpret_cast<const unsigned*>(xb + (size_t)s2 * DIM_IN)[lane];
        unsigned u3 = reinterpret_cast<const unsigned*>(xb + (size_t)s3 * DIM_IN)[lane];
        a0 += bflo(u0) + bflo(u1);
        a1 += bfhi(u0) + bfhi(u1);
        b0 += bflo(u2) + bflo(u3);
        b1 += bfhi(u2) + bfhi(u3);
    }
    for (; e < end; ++e) {
        int s0 = csr[e];
        unsigned u0 = reinterpret_cast<const unsigned*>(xb + (size_t)s0 * DIM_IN)[lane];
        a0 += bflo(u0);
        a1 += bfhi(u0);
    }
    float d = deg_inv[node];
    float r0 = (a0 + b0) * d;
    float r1 = (a1 + b1) * d;
    unsigned short q0 = __builtin_bit_cast(unsigned short, (__bf16)r0);
    unsigned short q1 = __builtin_bit_cast(unsigned short, (__bf16)r1);
    reinterpret_cast<unsigned*>(mb + (size_t)node * DIM_IN)[lane] =
        (unsigned)q0 | ((unsigned)q1 << 16);
}

// ---------------- GELU (tanh form, branch-free) ----------------------------
__device__ __forceinline__ float gelu_f(float h) {
    float u = h * h;
    float inner = h * (0.7978845608f + 0.0356774081f * u);
    float a = __builtin_amdgcn_exp2f(-2.8853900818f * __builtin_fabsf(inner));
    float t = (1.f - a) * __builtin_amdgcn_rcpf(1.f + a);
    t = __builtin_copysignf(t, inner);
    return 0.5f * h * (1.f + t);
}

// ---------------- MFMA GEMM + bias + GELU ----------------------------------
// 512 thr = 8 waves; block owns NPB=64 nodes in 2 sub-tiles of 32; wave w
// owns out cols [w*32, w*32+32). 1563 blocks -> 48 waves/CU of TLP.
// mfma(A=W_frag, B=m_frag): D col = lane&15 = node, row = kg*4+reg = out;
// lane's f32x4 = 4 consecutive out channels of one node -> plain float4 store.
__global__ __launch_bounds__(512, 4) void k_gemm(
    const unsigned short* __restrict__ mb,
    const unsigned short* __restrict__ Wb,
    const float* __restrict__ bias,
    float* __restrict__ out)
{
    const int wave = threadIdx.x >> 6;
    const int lane = threadIdx.x & 63;
    const int lr = lane & 15;
    const int kg = lane >> 4;
    const int o0 = wave * 32;
    const int nb0 = blockIdx.x * NPB;

    bf16x8 wfr[2][4];
#pragma unroll
    for (int mt = 0; mt < 2; ++mt)
#pragma unroll
        for (int ks = 0; ks < 4; ++ks)
            wfr[mt][ks] = *reinterpret_cast<const bf16x8*>(
                Wb + (size_t)(o0 + mt * 16 + lr) * DIM_IN + ks * 32 + kg * 8);

    f32x4 bias4[2];
#pragma unroll
    for (int mt = 0; mt < 2; ++mt)
        bias4[mt] = *reinterpret_cast<const f32x4*>(bias + o0 + mt * 16 + kg * 4);

#pragma unroll
    for (int st = 0; st < NPB / 32; ++st) {
        const int nb = nb0 + st * 32;
        if (nb >= N_NODES) break;

        bf16x8 mfr[2][4];
#pragma unroll
        for (int nt = 0; nt < 2; ++nt) {
            const unsigned short* brow = mb + (size_t)(nb + nt * 16 + lr) * DIM_IN;
#pragma unroll
            for (int ks = 0; ks < 4; ++ks)
                mfr[nt][ks] = *reinterpret_cast<const bf16x8*>(brow + ks * 32 + kg * 8);
        }

        f32x4 acc[2][2] = {};
#pragma unroll
        for (int ks = 0; ks < 4; ++ks)
#pragma unroll
            for (int mt = 0; mt < 2; ++mt)
#pragma unroll
                for (int nt = 0; nt < 2; ++nt)
                    acc[mt][nt] = __builtin_amdgcn_mfma_f32_16x16x32_bf16(
                        wfr[mt][ks], mfr[nt][ks], acc[mt][nt], 0, 0, 0);

#pragma unroll
        for (int nt = 0; nt < 2; ++nt) {
            const int node = nb + nt * 16 + lr;
            float* orow = out + (size_t)node * DIM_OUT + o0 + kg * 4;
#pragma unroll
            for (int mt = 0; mt < 2; ++mt) {
                f32x4 h = acc[mt][nt] + bias4[mt];
                f32x4 g;
                g[0] = gelu_f(h[0]);
                g[1] = gelu_f(h[1]);
                g[2] = gelu_f(h[2]);
                g[3] = gelu_f(h[3]);
                *reinterpret_cast<f32x4*>(orow + mt * 16) = g;
            }
        }
    }
}

extern "C" void kernel_launch(void* const* d_in, const int* in_sizes, int n_in,
                              void* d_out, int out_size, void* d_ws, size_t ws_size,
                              hipStream_t stream) {
    const float* x       = (const float*)d_in[0];
    const int*   ei      = (const int*)d_in[1];
    const float* deg_inv = (const float*)d_in[2];
    const float* W       = (const float*)d_in[3];
    const float* bias    = (const float*)d_in[4];
    float*       out     = (float*)d_out;

    const int* src = ei;
    const int* dst = ei + N_EDGES;

    // ws layout: mb | counts | state(128) | incl | cursor | csr | Wb | xb
    unsigned short* mb = (unsigned short*)d_ws;
    size_t mb_bytes = (size_t)N_NODES * DIM_IN * sizeof(unsigned short);   // 25.6 MB
    int*      counts = (int*)((char*)d_ws + mb_bytes);
    unsigned* state  = (unsigned*)(counts + N_NODES);
    int*      incl   = (int*)(state + 128);
    int*      cursor = incl + N_NODES;
    int*      csr    = cursor + N_NODES;
    unsigned short* Wb = (unsigned short*)(csr + N_EDGES);
    unsigned short* xb = Wb + DIM_IN * DIM_OUT;

    // zero counts + lookback state in one memset
    hipMemsetAsync(counts, 0, (N_NODES + 128) * sizeof(int), stream);
    k_prep<<<(N_NODES * DIM_IN / 4) / 256, 256, 0, stream>>>(x, W, dst, xb, Wb, counts);
    k_scan<<<SCAN_NB, 1024, 0, stream>>>(counts, incl, cursor, state);
    k_fill<<<N_EDGES / 256, 256, 0, stream>>>(src, dst, cursor, csr);
    k_agg <<<N_NODES / 4, 256, 0, stream>>>(xb, csr, incl, counts, deg_inv, mb);
    k_gemm<<<(N_NODES + NPB - 1) / NPB, 512, 0, stream>>>(mb, Wb, bias, out);
}

// Round 10
// 187.602 us; speedup vs baseline: 1.3207x; 1.0122x over previous
//
#include <hip/hip_runtime.h>
#include <math.h>

#define N_NODES 100000
#define N_EDGES 800000
#define DIM_IN 128
#define DIM_OUT 256
#define NPB 64     // nodes per GEMM block: 2 sub-tiles of 32
#define SCAN_NB 98 // ceil(100000/1024)

typedef __bf16 bf16x8 __attribute__((ext_vector_type(8)));
typedef float  f32x4  __attribute__((ext_vector_type(4)));

// ---------------- zero counts + lookback state (replaces runtime memset) ---
// Round-9 rocprof showed the hipMemsetAsync fillBufferAligned dispatch taking
// ~60us for a 391KB fill; a plain kernel does it in ~3us.
__global__ __launch_bounds__(1024) void k_zero(int* __restrict__ p) {
    int i = blockIdx.x * 1024 + threadIdx.x;
    if (i < N_NODES + 128) p[i] = 0;
}

// ---------------- prep: cvtX + cvtW + dst-count (counts pre-zeroed) --------
// grid exact: 12500*256 = 3.2M threads = x float4 elements.
__global__ __launch_bounds__(256) void k_prep(const float* __restrict__ x,
                                              const float* __restrict__ W,
                                              const int* __restrict__ dst,
                                              unsigned short* __restrict__ xb,
                                              unsigned short* __restrict__ Wb,
                                              int* __restrict__ counts) {
    int i = blockIdx.x * 256 + threadIdx.x;
    const float4 v = reinterpret_cast<const float4*>(x)[i];
    unsigned short s0 = __builtin_bit_cast(unsigned short, (__bf16)v.x);
    unsigned short s1 = __builtin_bit_cast(unsigned short, (__bf16)v.y);
    unsigned short s2 = __builtin_bit_cast(unsigned short, (__bf16)v.z);
    unsigned short s3 = __builtin_bit_cast(unsigned short, (__bf16)v.w);
    uint2 o;
    o.x = (unsigned)s0 | ((unsigned)s1 << 16);
    o.y = (unsigned)s2 | ((unsigned)s3 << 16);
    reinterpret_cast<uint2*>(xb)[i] = o;
    if (i < DIM_IN * DIM_OUT) Wb[i] = __builtin_bit_cast(unsigned short, (__bf16)W[i]);
    if (i < N_EDGES) atomicAdd(&counts[dst[i]], 1);
}

// ---------------- single-dispatch decoupled-lookback scan ------------------
// 98 blocks x 1024 thr; all co-resident on 256 CUs -> spin-wait is safe.
// state[b]: 0 = not ready; flag(bits30-31)=1 -> aggregate; =2 -> inclusive.
__global__ __launch_bounds__(1024) void k_scan(const int* __restrict__ counts,
                                               int* __restrict__ incl,
                                               int* __restrict__ cursor,
                                               unsigned* __restrict__ state) {
    __shared__ int ws[16];
    __shared__ int sExc;
    const int tid = threadIdx.x, lane = tid & 63, wid = tid >> 6;
    const int b = blockIdx.x;
    const int i = b * 1024 + tid;
    const int c = (i < N_NODES) ? counts[i] : 0;
    int v = c;
#pragma unroll
    for (int d = 1; d < 64; d <<= 1) {
        int t = __shfl_up(v, d, 64);
        if (lane >= d) v += t;
    }
    if (lane == 63) ws[wid] = v;
    __syncthreads();
    if (wid == 0) {
        int s = (lane < 16) ? ws[lane] : 0;
#pragma unroll
        for (int d = 1; d < 16; d <<= 1) {
            int t = __shfl_up(s, d, 64);
            if (lane >= d) s += t;
        }
        if (lane < 16) ws[lane] = s;
    }
    __syncthreads();
    const int total = ws[15];
    if (wid > 0) v += ws[wid - 1];
    if (tid == 0 && b > 0)
        __hip_atomic_store(&state[b], (1u << 30) | (unsigned)total,
                           __ATOMIC_RELEASE, __HIP_MEMORY_SCOPE_AGENT);
    if (wid == 0) {
        int exclusive = 0;
        if (b > 0) {
            int look = b - 1;
            for (;;) {
                int idx = look - lane;
                unsigned s;
                bool rdy;
                do {
                    s = (idx >= 0) ? __hip_atomic_load(&state[idx], __ATOMIC_ACQUIRE,
                                                       __HIP_MEMORY_SCOPE_AGENT)
                                   : (2u << 30);
                    rdy = (s >> 30) != 0u;
                } while (!__all(rdy));
                unsigned long long incmask = __ballot((s >> 30) == 2u);
                int firstInc = (incmask == 0ull) ? 64 : (__ffsll(incmask) - 1);
                int contrib = (lane <= firstInc) ? (int)(s & 0x3FFFFFFFu) : 0;
#pragma unroll
                for (int d = 32; d >= 1; d >>= 1) contrib += __shfl_down(contrib, d, 64);
                contrib = __shfl(contrib, 0, 64);
                exclusive += contrib;
                if (firstInc < 64) break;   // found an inclusive predecessor
                look -= 64;                 // window exhausted: step back
            }
        }
        if (lane == 0) {
            sExc = exclusive;
            __hip_atomic_store(&state[b], (2u << 30) | (unsigned)(exclusive + total),
                               __ATOMIC_RELEASE, __HIP_MEMORY_SCOPE_AGENT);
        }
    }
    __syncthreads();
    v += sExc;
    if (i < N_NODES) {
        incl[i] = v;          // global inclusive scan
        cursor[i] = v - c;    // row start (exclusive)
    }
}

__global__ __launch_bounds__(256) void k_fill(const int* __restrict__ src,
                                              const int* __restrict__ dst,
                                              int* __restrict__ cursor,
                                              int* __restrict__ csr) {
    int e = blockIdx.x * 256 + threadIdx.x;   // grid exact: 800000/256
    int pos = atomicAdd(&cursor[dst[e]], 1);
    csr[pos] = src[e];
}

// ---------------- Aggregate: mb[n] = bf16(deg_inv[n] * sum xb[src]) --------
// One wave per node (100k waves of TLP); lane holds one packed bf16x2 (4 B)
// of the 256 B row -> fully-coalesced 256 B read per edge. x8 unroll with 4
// accumulator chains keeps 8 gathers in flight (L3-latency-bound).
__device__ __forceinline__ float bflo(unsigned u) {
    return __builtin_bit_cast(float, u << 16);
}
__device__ __forceinline__ float bfhi(unsigned u) {
    return __builtin_bit_cast(float, u & 0xffff0000u);
}

__global__ __launch_bounds__(256) void k_agg(const unsigned short* __restrict__ xb,
                                             const int* __restrict__ csr,
                                             const int* __restrict__ incl,
                                             const int* __restrict__ counts,
                                             const float* __restrict__ deg_inv,
                                             unsigned short* __restrict__ mb) {
    int wave = threadIdx.x >> 6;
    int lane = threadIdx.x & 63;
    int node = blockIdx.x * 4 + wave;        // grid exact: 25000*4
    int end = __builtin_amdgcn_readfirstlane(incl[node]);
    int beg = end - __builtin_amdgcn_readfirstlane(counts[node]);
    float a0 = 0.f, a1 = 0.f, b0 = 0.f, b1 = 0.f;
    float c0 = 0.f, c1 = 0.f, d0 = 0.f, d1 = 0.f;
    int e = beg;
    for (; e + 7 < end; e += 8) {
        int s0 = csr[e],     s1 = csr[e + 1], s2 = csr[e + 2], s3 = csr[e + 3];
        int s4 = csr[e + 4], s5 = csr[e + 5], s6 = csr[e + 6], s7 = csr[e + 7];
        unsigned u0 = reinterpret_cast<const unsigned*>(xb + (size_t)s0 * DIM_IN)[lane];
        unsigned u1 = reinterpret_cast<const unsigned*>(xb + (size_t)s1 * DIM_IN)[lane];
        unsigned u2 = reinterpret_cast<const unsigned*>(xb + (size_t)s2 * DIM_IN)[lane];
        unsigned u3 = reinterpret_cast<const unsigned*>(xb + (size_t)s3 * DIM_IN)[lane];
        unsigned u4 = reinterpret_cast<const unsigned*>(xb + (size_t)s4 * DIM_IN)[lane];
        unsigned u5 = reinterpret_cast<const unsigned*>(xb + (size_t)s5 * DIM_IN)[lane];
        unsigned u6 = reinterpret_cast<const unsigned*>(xb + (size_t)s6 * DIM_IN)[lane];
        unsigned u7 = reinterpret_cast<const unsigned*>(xb + (size_t)s7 * DIM_IN)[lane];
        a0 += bflo(u0) + bflo(u1);  a1 += bfhi(u0) + bfhi(u1);
        b0 += bflo(u2) + bflo(u3);  b1 += bfhi(u2) + bfhi(u3);
        c0 += bflo(u4) + bflo(u5);  c1 += bfhi(u4) + bfhi(u5);
        d0 += bflo(u6) + bflo(u7);  d1 += bfhi(u6) + bfhi(u7);
    }
    for (; e + 3 < end; e += 4) {
        int s0 = csr[e], s1 = csr[e + 1], s2 = csr[e + 2], s3 = csr[e + 3];
        unsigned u0 = reinterpret_cast<const unsigned*>(xb + (size_t)s0 * DIM_IN)[lane];
        unsigned u1 = reinterpret_cast<const unsigned*>(xb + (size_t)s1 * DIM_IN)[lane];
        unsigned u2 = reinterpret_cast<const unsigned*>(xb + (size_t)s2 * DIM_IN)[lane];
        unsigned u3 = reinterpret_cast<const unsigned*>(xb + (size_t)s3 * DIM_IN)[lane];
        a0 += bflo(u0) + bflo(u1);  a1 += bfhi(u0) + bfhi(u1);
        b0 += bflo(u2) + bflo(u3);  b1 += bfhi(u2) + bfhi(u3);
    }
    for (; e < end; ++e) {
        int s0 = csr[e];
        unsigned u0 = reinterpret_cast<const unsigned*>(xb + (size_t)s0 * DIM_IN)[lane];
        a0 += bflo(u0);
        a1 += bfhi(u0);
    }
    float d = deg_inv[node];
    float r0 = ((a0 + b0) + (c0 + d0)) * d;
    float r1 = ((a1 + b1) + (c1 + d1)) * d;
    unsigned short q0 = __builtin_bit_cast(unsigned short, (__bf16)r0);
    unsigned short q1 = __builtin_bit_cast(unsigned short, (__bf16)r1);
    reinterpret_cast<unsigned*>(mb + (size_t)node * DIM_IN)[lane] =
        (unsigned)q0 | ((unsigned)q1 << 16);
}

// ---------------- GELU (tanh form, branch-free) ----------------------------
__device__ __forceinline__ float gelu_f(float h) {
    float u = h * h;
    float inner = h * (0.7978845608f + 0.0356774081f * u);
    float a = __builtin_amdgcn_exp2f(-2.8853900818f * __builtin_fabsf(inner));
    float t = (1.f - a) * __builtin_amdgcn_rcpf(1.f + a);
    t = __builtin_copysignf(t, inner);
    return 0.5f * h * (1.f + t);
}

// ---------------- MFMA GEMM + bias + GELU ----------------------------------
// 512 thr = 8 waves; block owns NPB=64 nodes in 2 sub-tiles of 32; wave w
// owns out cols [w*32, w*32+32). 1563 blocks -> plenty of TLP.
// mfma(A=W_frag, B=m_frag): D col = lane&15 = node, row = kg*4+reg = out;
// lane's f32x4 = 4 consecutive out channels of one node -> plain float4 store.
__global__ __launch_bounds__(512, 4) void k_gemm(
    const unsigned short* __restrict__ mb,
    const unsigned short* __restrict__ Wb,
    const float* __restrict__ bias,
    float* __restrict__ out)
{
    const int wave = threadIdx.x >> 6;
    const int lane = threadIdx.x & 63;
    const int lr = lane & 15;
    const int kg = lane >> 4;
    const int o0 = wave * 32;
    const int nb0 = blockIdx.x * NPB;

    bf16x8 wfr[2][4];
#pragma unroll
    for (int mt = 0; mt < 2; ++mt)
#pragma unroll
        for (int ks = 0; ks < 4; ++ks)
            wfr[mt][ks] = *reinterpret_cast<const bf16x8*>(
                Wb + (size_t)(o0 + mt * 16 + lr) * DIM_IN + ks * 32 + kg * 8);

    f32x4 bias4[2];
#pragma unroll
    for (int mt = 0; mt < 2; ++mt)
        bias4[mt] = *reinterpret_cast<const f32x4*>(bias + o0 + mt * 16 + kg * 4);

#pragma unroll
    for (int st = 0; st < NPB / 32; ++st) {
        const int nb = nb0 + st * 32;
        if (nb >= N_NODES) break;

        bf16x8 mfr[2][4];
#pragma unroll
        for (int nt = 0; nt < 2; ++nt) {
            const unsigned short* brow = mb + (size_t)(nb + nt * 16 + lr) * DIM_IN;
#pragma unroll
            for (int ks = 0; ks < 4; ++ks)
                mfr[nt][ks] = *reinterpret_cast<const bf16x8*>(brow + ks * 32 + kg * 8);
        }

        f32x4 acc[2][2] = {};
#pragma unroll
        for (int ks = 0; ks < 4; ++ks)
#pragma unroll
            for (int mt = 0; mt < 2; ++mt)
#pragma unroll
                for (int nt = 0; nt < 2; ++nt)
                    acc[mt][nt] = __builtin_amdgcn_mfma_f32_16x16x32_bf16(
                        wfr[mt][ks], mfr[nt][ks], acc[mt][nt], 0, 0, 0);

#pragma unroll
        for (int nt = 0; nt < 2; ++nt) {
            const int node = nb + nt * 16 + lr;
            float* orow = out + (size_t)node * DIM_OUT + o0 + kg * 4;
#pragma unroll
            for (int mt = 0; mt < 2; ++mt) {
                f32x4 h = acc[mt][nt] + bias4[mt];
                f32x4 g;
                g[0] = gelu_f(h[0]);
                g[1] = gelu_f(h[1]);
                g[2] = gelu_f(h[2]);
                g[3] = gelu_f(h[3]);
                *reinterpret_cast<f32x4*>(orow + mt * 16) = g;
            }
        }
    }
}

extern "C" void kernel_launch(void* const* d_in, const int* in_sizes, int n_in,
                              void* d_out, int out_size, void* d_ws, size_t ws_size,
                              hipStream_t stream) {
    const float* x       = (const float*)d_in[0];
    const int*   ei      = (const int*)d_in[1];
    const float* deg_inv = (const float*)d_in[2];
    const float* W       = (const float*)d_in[3];
    const float* bias    = (const float*)d_in[4];
    float*       out     = (float*)d_out;

    const int* src = ei;
    const int* dst = ei + N_EDGES;

    // ws layout: mb | counts | state(128) | incl | cursor | csr | Wb | xb
    unsigned short* mb = (unsigned short*)d_ws;
    size_t mb_bytes = (size_t)N_NODES * DIM_IN * sizeof(unsigned short);   // 25.6 MB
    int*      counts = (int*)((char*)d_ws + mb_bytes);
    unsigned* state  = (unsigned*)(counts + N_NODES);
    int*      incl   = (int*)(state + 128);
    int*      cursor = incl + N_NODES;
    int*      csr    = cursor + N_NODES;
    unsigned short* Wb = (unsigned short*)(csr + N_EDGES);
    unsigned short* xb = Wb + DIM_IN * DIM_OUT;

    k_zero<<<SCAN_NB, 1024, 0, stream>>>(counts);   // counts + state
    k_prep<<<(N_NODES * DIM_IN / 4) / 256, 256, 0, stream>>>(x, W, dst, xb, Wb, counts);
    k_scan<<<SCAN_NB, 1024, 0, stream>>>(counts, incl, cursor, state);
    k_fill<<<N_EDGES / 256, 256, 0, stream>>>(src, dst, cursor, csr);
    k_agg <<<N_NODES / 4, 256, 0, stream>>>(xb, csr, incl, counts, deg_inv, mb);
    k_gemm<<<(N_NODES + NPB - 1) / NPB, 512, 0, stream>>>(mb, Wb, bias, out);
}